// Round 1
// baseline (131096.179 us; speedup 1.0000x reference)
//
#include <hip/hip_runtime.h>

#define T_STEPS 16384
#define HID     1000
#define NB      250      // workgroups: each owns 4 hidden units
#define NTH     256      // 4 waves
#define RS      1096     // LSTM LDS row stride (floats): 1000 W_hh + pad + 18 W_ih + bias + pad
#define MS      1024     // MLP  LDS row stride (floats)

typedef unsigned int       uint32;
typedef unsigned long long u64;

__device__ __forceinline__ u64 ag_load_u64(const u64* p) {
  return __hip_atomic_load((u64*)p, __ATOMIC_RELAXED, __HIP_MEMORY_SCOPE_AGENT);
}
__device__ __forceinline__ void ag_store_f(float* p, float v) {
  __hip_atomic_store(p, v, __ATOMIC_RELAXED, __HIP_MEMORY_SCOPE_AGENT);
}

// All-block flag wait: flags[i] >= tgt for all i. One writer per flag, so no
// atomic contention; loads are agent-scope (bypass L1/L2 -> LLC, cross-XCD safe).
__device__ __forceinline__ void wait_flags(uint32* flags, uint32 tgt, int tid) {
  for (;;) {
    int ok = 1;
    if (tid < 64) {
      for (int f = tid; f < NB; f += 64) {
        uint32 v = __hip_atomic_load(&flags[f], __ATOMIC_RELAXED, __HIP_MEMORY_SCOPE_AGENT);
        ok &= (int)(v >= tgt);
      }
    }
    if (__syncthreads_and(ok)) return;
    __builtin_amdgcn_s_sleep(1);
  }
}

// Gather 1000 floats (published by 250 WGs across XCDs) into LDS via 8B
// agent-scope loads. Optionally apply relu (for the first MLP layer input).
__device__ __forceinline__ void stage_vec(const float* src, float* lds_v, int tid, bool relu) {
  const u64* s8 = (const u64*)src;
#pragma unroll
  for (int q = 0; q < 2; ++q) {
    int p = tid + q * NTH;
    if (p < 500) {
      u64 uv = ag_load_u64(&s8[p]);
      union { u64 u; float f[2]; } cv; cv.u = uv;
      float a = cv.f[0], b = cv.f[1];
      if (relu) { a = fmaxf(a, 0.f); b = fmaxf(b, 0.f); }
      lds_v[2 * p]     = a;
      lds_v[2 * p + 1] = b;
    }
  }
}

__global__ __launch_bounds__(NTH) void lstm_mlp_kernel(
    const float* __restrict__ x,    const float* __restrict__ h0,
    const float* __restrict__ c0,   const float* __restrict__ W_ih,
    const float* __restrict__ W_hh, const float* __restrict__ b_ih,
    const float* __restrict__ b_hh,
    const float* __restrict__ W1, const float* __restrict__ b1,
    const float* __restrict__ W2, const float* __restrict__ b2,
    const float* __restrict__ W3, const float* __restrict__ b3,
    const float* __restrict__ W4, const float* __restrict__ b4,
    const float* __restrict__ Wo, const float* __restrict__ bo,
    float* __restrict__ buf0, float* __restrict__ buf1,
    uint32* __restrict__ flags, float* __restrict__ out)
{
  // ~140KB static LDS -> exactly 1 WG/CU (forces spread over 250 CUs; all resident)
  __shared__ __align__(16) float lds_W[16 * RS];   // 16 LSTM gate rows (W_hh | pad | W_ih | bias)
  __shared__ __align__(16) float lds_M[16 * MS];   // 4 layers x 4 MLP rows
  __shared__ __align__(16) float lds_v[RS];        // [h(1000) | 0 | x_t(18) | 1.0 | 0]
  __shared__ float lds_b[16];                      // MLP biases
  __shared__ float lds_log[3];

  const int tid   = threadIdx.x;
  const int bid   = blockIdx.x;
  const int wv    = tid >> 6;    // wave 0..3  <-> hidden unit baseu+wv
  const int lane  = tid & 63;
  const int gate  = lane >> 4;   // 0..3 <-> i,f,g,o
  const int l16   = lane & 15;   // 16 lanes per gate row
  const int baseu = bid * 4;

  // ---------------- init: stage all weights into LDS (W_hh read from HBM once) ----
  for (int rr = 0; rr < 16; ++rr) {           // rr = w*4 + g  (wave w, gate g)
    const int g = rr & 3, w = rr >> 2;
    const int grow = g * HID + baseu + w;     // global gate row in [0,4000)
    const float* src = W_hh + (size_t)grow * HID;
    float* dst = lds_W + rr * RS;
    for (int k4 = tid; k4 < 250; k4 += NTH)
      *(float4*)&dst[k4 * 4] = *(const float4*)&src[k4 * 4];
    if (tid < 96) {                           // tail: [1000,1096)
      int k = 1000 + tid;
      float v = 0.f;
      if (k >= 1024 && k < 1042)      v = W_ih[(size_t)grow * 18 + (k - 1024)];
      else if (k == 1042)             v = b_ih[grow] + b_hh[grow];
      dst[k] = v;
    }
  }
  for (int rr = 0; rr < 16; ++rr) {           // rr = L*4 + u
    const int L = rr >> 2, u = rr & 3;
    const float* WL = (L == 0) ? W1 : (L == 1) ? W2 : (L == 2) ? W3 : W4;
    const float* bL = (L == 0) ? b1 : (L == 1) ? b2 : (L == 2) ? b3 : b4;
    const int grow = baseu + u;
    const float* src = WL + (size_t)grow * HID;
    float* dst = lds_M + rr * MS;
    for (int k4 = tid; k4 < 250; k4 += NTH)
      *(float4*)&dst[k4 * 4] = *(const float4*)&src[k4 * 4];
    if (tid < 24) dst[1000 + tid] = 0.f;
    if (tid == 0) lds_b[rr] = bL[grow];
  }
  if (tid < 96) {                             // vec pads: zeros, 1.0 at bias slot
    int k = 1000 + tid;
    lds_v[k] = (k == 1042) ? 1.f : 0.f;
  }
  float c_state = 0.f;
  if (lane == 0) c_state = c0[baseu + wv];
  __syncthreads();

  // ---------------- the 16384-step recurrence --------------------------------
  for (int t = 1; t <= T_STEPS; ++t) {
    if (t > 1) wait_flags(flags, (uint32)(t - 1), tid);

    // stage x_t and h_{t-1} into lds_v  (poll barrier guarantees prev dot done)
    if (tid < 18) lds_v[1024 + tid] = x[(size_t)(t - 1) * 18 + tid];
    const float* hsrc = (t == 1) ? h0 : (((t - 1) & 1) ? buf1 : buf0);
    stage_vec(hsrc, lds_v, tid, false);
    __syncthreads();

    // 16 gate rows: wave wv, gate group; 16 lanes/row, b128 strided dot over 1088
    const float* wrow = lds_W + (wv * 4 + gate) * RS + l16 * 4;
    const float* vrow = lds_v + l16 * 4;
    float4 acc{0.f, 0.f, 0.f, 0.f};
#pragma unroll
    for (int j = 0; j < 17; ++j) {
      float4 w4 = *(const float4*)(wrow + 64 * j);
      float4 v4 = *(const float4*)(vrow + 64 * j);
      acc.x = fmaf(w4.x, v4.x, acc.x);
      acc.y = fmaf(w4.y, v4.y, acc.y);
      acc.z = fmaf(w4.z, v4.z, acc.z);
      acc.w = fmaf(w4.w, v4.w, acc.w);
    }
    float s = (acc.x + acc.y) + (acc.z + acc.w);
    s += __shfl_xor(s, 1); s += __shfl_xor(s, 2);
    s += __shfl_xor(s, 4); s += __shfl_xor(s, 8);

    // activations in parallel on the 4 gate-holder groups: sigmoid / tanh(=2sig(2x)-1)
    float pre = (gate == 2) ? 2.f * s : s;
    float sg  = 1.f / (1.f + __expf(-pre));          // safe: exp(+inf)->inf -> 0
    float act = (gate == 2) ? (2.f * sg - 1.f) : sg;
    float a_i = __shfl(act, 0);
    float a_f = __shfl(act, 16);
    float a_g = __shfl(act, 32);
    float a_o = __shfl(act, 48);

    if (lane == 0) {
      c_state  = fmaf(a_f, c_state, a_i * a_g);
      float ac = fabsf(c_state);
      float e  = __expf(-2.f * ac);                  // in (0,1], overflow-safe tanh
      float th = (1.f - e) / (1.f + e);
      th = copysignf(th, c_state);
      float hv = a_o * th;
      float* dbuf = (t & 1) ? buf1 : buf0;
      ag_store_f(&dbuf[baseu + wv], hv);             // sc0+sc1 write-through
    }
    __syncthreads();   // each wave drains vmcnt(0) before barrier -> stores visible
    if (tid == 0)
      __hip_atomic_store(&flags[bid], (uint32)t, __ATOMIC_RELEASE, __HIP_MEMORY_SCOPE_AGENT);
    __syncthreads();   // own flag visible before next poll
  }

  // ---------------- MLP: 4 virtual rounds, wave wv computes unit baseu+wv ----
  for (int r = 1; r <= 4; ++r) {
    wait_flags(flags, (uint32)(T_STEPS + r - 1), tid);
    const float* hsrc = ((T_STEPS + r - 1) & 1) ? buf1 : buf0;
    stage_vec(hsrc, lds_v, tid, /*relu on LSTM output only*/ (r == 1));
    __syncthreads();

    const float* wrow = lds_M + ((r - 1) * 4 + wv) * MS + lane * 4;
    const float* vrow = lds_v + lane * 4;
    float4 acc{0.f, 0.f, 0.f, 0.f};
#pragma unroll
    for (int j = 0; j < 4; ++j) {
      float4 w4 = *(const float4*)(wrow + 256 * j);
      float4 v4 = *(const float4*)(vrow + 256 * j);
      acc.x = fmaf(w4.x, v4.x, acc.x);
      acc.y = fmaf(w4.y, v4.y, acc.y);
      acc.z = fmaf(w4.z, v4.z, acc.z);
      acc.w = fmaf(w4.w, v4.w, acc.w);
    }
    float s = (acc.x + acc.y) + (acc.z + acc.w);
    s += __shfl_xor(s, 1);  s += __shfl_xor(s, 2);  s += __shfl_xor(s, 4);
    s += __shfl_xor(s, 8);  s += __shfl_xor(s, 16); s += __shfl_xor(s, 32);

    if (lane == 0) {
      float y = fmaxf(s + lds_b[(r - 1) * 4 + wv], 0.f);   // relu'd activation
      float* dbuf = ((T_STEPS + r) & 1) ? buf1 : buf0;
      ag_store_f(&dbuf[baseu + wv], y);
    }
    __syncthreads();
    if (tid == 0)
      __hip_atomic_store(&flags[bid], (uint32)(T_STEPS + r), __ATOMIC_RELEASE, __HIP_MEMORY_SCOPE_AGENT);
    __syncthreads();
  }

  // ---------------- final: WG0 computes logits + softmax ---------------------
  if (bid == 0) {
    wait_flags(flags, (uint32)(T_STEPS + 4), tid);
    const float* hsrc = ((T_STEPS + 4) & 1) ? buf1 : buf0;
    stage_vec(hsrc, lds_v, tid, false);
    __syncthreads();

    float s = 0.f;
    if (wv < 3) {
      const float* wo = Wo + (size_t)wv * HID;
      float4 acc{0.f, 0.f, 0.f, 0.f};
#pragma unroll
      for (int j = 0; j < 4; ++j) {
        int f4 = lane + 64 * j;
        if (f4 < 250) {
          float4 w4 = *(const float4*)(wo + f4 * 4);
          float4 v4 = *(const float4*)(lds_v + f4 * 4);
          acc.x = fmaf(w4.x, v4.x, acc.x);
          acc.y = fmaf(w4.y, v4.y, acc.y);
          acc.z = fmaf(w4.z, v4.z, acc.z);
          acc.w = fmaf(w4.w, v4.w, acc.w);
        }
      }
      s = (acc.x + acc.y) + (acc.z + acc.w);
      s += __shfl_xor(s, 1);  s += __shfl_xor(s, 2);  s += __shfl_xor(s, 4);
      s += __shfl_xor(s, 8);  s += __shfl_xor(s, 16); s += __shfl_xor(s, 32);
    }
    if (wv < 3 && lane == 0) lds_log[wv] = s + bo[wv];
    __syncthreads();
    if (tid == 0) {
      float l0 = lds_log[0], l1 = lds_log[1], l2 = lds_log[2];
      float m  = fmaxf(l0, fmaxf(l1, l2));
      float e0 = __expf(l0 - m), e1 = __expf(l1 - m), e2 = __expf(l2 - m);
      float inv = 1.f / (e0 + e1 + e2);
      out[0] = e0 * inv; out[1] = e1 * inv; out[2] = e2 * inv;
    }
  }
}

extern "C" void kernel_launch(void* const* d_in, const int* in_sizes, int n_in,
                              void* d_out, int out_size, void* d_ws, size_t ws_size,
                              hipStream_t stream) {
  const float* x    = (const float*)d_in[0];
  const float* h0   = (const float*)d_in[1];
  const float* c0   = (const float*)d_in[2];
  const float* W_ih = (const float*)d_in[3];
  const float* W_hh = (const float*)d_in[4];
  const float* b_ih = (const float*)d_in[5];
  const float* b_hh = (const float*)d_in[6];
  const float* W1 = (const float*)d_in[7];
  const float* b1 = (const float*)d_in[8];
  const float* W2 = (const float*)d_in[9];
  const float* b2 = (const float*)d_in[10];
  const float* W3 = (const float*)d_in[11];
  const float* b3 = (const float*)d_in[12];
  const float* W4 = (const float*)d_in[13];
  const float* b4 = (const float*)d_in[14];
  const float* Wo = (const float*)d_in[15];
  const float* bo = (const float*)d_in[16];

  // ws layout: buf0 [0,1024) floats | buf1 [1024,2048) | flags (250 u32)
  float* buf0 = (float*)d_ws;
  float* buf1 = buf0 + 1024;
  unsigned int* flags = (unsigned int*)(buf0 + 2048);

  // flags must be zeroed EVERY launch (d_ws poisoned once, then never restored)
  hipMemsetAsync(flags, 0, NB * sizeof(unsigned int), stream);

  hipLaunchKernelGGL(lstm_mlp_kernel, dim3(NB), dim3(NTH), 0, stream,
                     x, h0, c0, W_ih, W_hh, b_ih, b_hh,
                     W1, b1, W2, b2, W3, b3, W4, b4, Wo, bo,
                     buf0, buf1, flags, (float*)d_out);
}

// Round 2
// 50563.440 us; speedup vs baseline: 2.5927x; 2.5927x over previous
//
#include <hip/hip_runtime.h>

#define T_STEPS 16384
#define HID     1000
#define NB      250      // workgroups; each owns 4 hidden units (wave w <-> unit 4*bid+w)
#define NTH     256      // 4 waves
#define RS      1024     // LDS row stride (floats): [W_hh(1000) | W_ih(18) | b(1) | 0 x5]
#define EPAR    8192     // u64s per parity buffer (1000 entries x 8-u64 = 64B stride)

typedef unsigned int       uint32;
typedef unsigned long long u64;

__device__ __forceinline__ u64 ag_load(const u64* p) {
  return __hip_atomic_load(p, __ATOMIC_RELAXED, __HIP_MEMORY_SCOPE_AGENT);
}
__device__ __forceinline__ void ag_store(u64* p, u64 v) {
  __hip_atomic_store(p, v, __ATOMIC_RELAXED, __HIP_MEMORY_SCOPE_AGENT);
}

// {float value (lo32) | seq (hi32)} -- 8B single-copy atomic: seq validates value.
__device__ __forceinline__ u64 pack_entry(float v, uint32 seq) {
  return ((u64)seq << 32) | (u64)__float_as_uint(v);
}

// Poll 4 entries (one producer WG's 4 units) until seq==tgt; write float4 to lds_v.
// Entries are 64B-strided => each cacheline polled by only 250 threads chip-wide.
__device__ __forceinline__ void gather4(const u64* pbase, uint32 tgt, int tid,
                                        float* lds_v, bool relu) {
  if (tid < NB) {
    const u64* pb = pbase + (size_t)tid * 32;   // 4 entries * 8-u64 stride
    u64 e0, e1, e2, e3;
    for (;;) {
      e0 = ag_load(pb +  0); e1 = ag_load(pb +  8);
      e2 = ag_load(pb + 16); e3 = ag_load(pb + 24);
      if ((uint32)(e0 >> 32) == tgt && (uint32)(e1 >> 32) == tgt &&
          (uint32)(e2 >> 32) == tgt && (uint32)(e3 >> 32) == tgt) break;
    }
    float4 hv;
    hv.x = __uint_as_float((uint32)e0);
    hv.y = __uint_as_float((uint32)e1);
    hv.z = __uint_as_float((uint32)e2);
    hv.w = __uint_as_float((uint32)e3);
    if (relu) {
      hv.x = fmaxf(hv.x, 0.f); hv.y = fmaxf(hv.y, 0.f);
      hv.z = fmaxf(hv.z, 0.f); hv.w = fmaxf(hv.w, 0.f);
    }
    *(float4*)&lds_v[4 * tid] = hv;
  }
}

__global__ __launch_bounds__(NTH) void lstm_mlp_kernel(
    const float* __restrict__ x,    const float* __restrict__ h0,
    const float* __restrict__ c0,   const float* __restrict__ W_ih,
    const float* __restrict__ W_hh, const float* __restrict__ b_ih,
    const float* __restrict__ b_hh,
    const float* __restrict__ W1, const float* __restrict__ b1,
    const float* __restrict__ W2, const float* __restrict__ b2,
    const float* __restrict__ W3, const float* __restrict__ b3,
    const float* __restrict__ W4, const float* __restrict__ b4,
    const float* __restrict__ Wo, const float* __restrict__ bo,
    u64* __restrict__ ws64, float* __restrict__ out)
{
  __shared__ __align__(16) float lds_W[16 * RS];  // 16 LSTM gate rows, 64 KB
  __shared__ __align__(16) float lds_v[RS];       // [h(1000) | x(18) | 1.0 | 0 x5]
  __shared__ float lds_log[3];

  const int tid   = threadIdx.x;
  const int bid   = blockIdx.x;
  const int wv    = tid >> 6;     // wave 0..3 <-> hidden unit 4*bid+wv
  const int lane  = tid & 63;
  const int lane4 = lane * 4;

  // -------- init: stage 16 LSTM gate rows into LDS (W_hh read from HBM once) ----
  for (int rr = 0; rr < 16; ++rr) {               // rr = w*4 + g
    const int w = rr >> 2, g = rr & 3;
    const int grow = g * HID + 4 * bid + w;       // global gate row in [0,4000)
    const float* src = W_hh + (size_t)grow * HID;
    float* dst = lds_W + rr * RS;
    for (int k4 = tid; k4 < 250; k4 += NTH)
      *(float4*)&dst[k4 * 4] = *(const float4*)&src[k4 * 4];
    if (tid < 24) {                               // tail [1000,1024)
      float v = 0.f;
      if (tid < 18)       v = W_ih[(size_t)grow * 18 + tid];
      else if (tid == 18) v = b_ih[grow] + b_hh[grow];
      dst[1000 + tid] = v;
    }
  }
  if (tid < 24) lds_v[1000 + tid] = (tid == 18) ? 1.f : 0.f;  // bias-one + zero pad

  float c_state = 0.f;
  if (lane == 0) c_state = c0[4 * bid + wv];
  __syncthreads();

  // -------- 16384-step recurrence ------------------------------------------------
  for (int t = 1; t <= T_STEPS; ++t) {
    if (tid < 18) lds_v[1000 + tid] = x[(size_t)(t - 1) * 18 + tid];  // x_t (no wait)

    if (t == 1) {
      if (tid < NB) *(float4*)&lds_v[4 * tid] = *(const float4*)&h0[4 * tid];
    } else {
      gather4(ws64 + ((t - 1) & 1) * EPAR, (uint32)(t - 1), tid, lds_v, false);
    }
    __syncthreads();

    // wave wv: 4 gate rows (i,f,g,o of its unit), full-wave dots, v reused
    float4 v0 = *(const float4*)&lds_v[lane4];
    float4 v1 = *(const float4*)&lds_v[256 + lane4];
    float4 v2 = *(const float4*)&lds_v[512 + lane4];
    float4 v3 = *(const float4*)&lds_v[768 + lane4];
    float acc[4];
#pragma unroll
    for (int g = 0; g < 4; ++g) {
      const float* wr = lds_W + (wv * 4 + g) * RS + lane4;
      float4 w0 = *(const float4*)(wr);
      float4 w1 = *(const float4*)(wr + 256);
      float4 w2 = *(const float4*)(wr + 512);
      float4 w3 = *(const float4*)(wr + 768);
      float s;
      s = w0.x * v0.x;        s = fmaf(w0.y, v0.y, s);
      s = fmaf(w0.z, v0.z, s); s = fmaf(w0.w, v0.w, s);
      s = fmaf(w1.x, v1.x, s); s = fmaf(w1.y, v1.y, s);
      s = fmaf(w1.z, v1.z, s); s = fmaf(w1.w, v1.w, s);
      s = fmaf(w2.x, v2.x, s); s = fmaf(w2.y, v2.y, s);
      s = fmaf(w2.z, v2.z, s); s = fmaf(w2.w, v2.w, s);
      s = fmaf(w3.x, v3.x, s); s = fmaf(w3.y, v3.y, s);
      s = fmaf(w3.z, v3.z, s); s = fmaf(w3.w, v3.w, s);
      acc[g] = s;
    }
    // phase A: reduce each acc within 4-lane groups
#pragma unroll
    for (int g = 0; g < 4; ++g) {
      acc[g] += __shfl_xor(acc[g], 1);
      acc[g] += __shfl_xor(acc[g], 2);
    }
    // phase B: lane picks its gate (lane&3), reduce across groups
    const int sel = lane & 3;
    float s = (sel == 0) ? acc[0] : (sel == 1) ? acc[1] : (sel == 2) ? acc[2] : acc[3];
    s += __shfl_xor(s, 4);  s += __shfl_xor(s, 8);
    s += __shfl_xor(s, 16); s += __shfl_xor(s, 32);

    // lanes 0..3 hold gates i,f,g,o; activations in parallel
    float pre = (sel == 2) ? 2.f * s : s;
    float sg  = 1.f / (1.f + __expf(-pre));
    float act = (sel == 2) ? (2.f * sg - 1.f) : sg;   // tanh(s) = 2*sig(2s)-1
    float a_i = __shfl(act, 0);
    float a_f = __shfl(act, 1);
    float a_g = __shfl(act, 2);
    float a_o = __shfl(act, 3);

    if (lane == 0) {
      c_state  = fmaf(a_f, c_state, a_i * a_g);
      float ac = fabsf(c_state);
      float e  = __expf(-2.f * ac);                   // overflow-safe tanh
      float th = (1.f - e) / (1.f + e);
      th = copysignf(th, c_state);
      float hv = a_o * th;
      ag_store(ws64 + (t & 1) * EPAR + (size_t)(4 * bid + wv) * 8,
               pack_entry(hv, (uint32)t));
    }
    __syncthreads();   // protect lds_v against next step's gather overwrite
  }

  // -------- MLP: 4 rounds, wave wv computes unit 4*bid+wv, weights from global ---
  for (int r = 1; r <= 4; ++r) {
    const uint32 sprev = (uint32)(T_STEPS + r - 1);
    gather4(ws64 + (sprev & 1) * EPAR, sprev, tid, lds_v, /*relu h_T*/ (r == 1));
    __syncthreads();

    const float* WL  = (r == 1) ? W1 : (r == 2) ? W2 : (r == 3) ? W3 : W4;
    const float* bLp = (r == 1) ? b1 : (r == 2) ? b2 : (r == 3) ? b3 : b4;
    const int u = 4 * bid + wv;
    const float* row = WL + (size_t)u * HID;

    float4 v0 = *(const float4*)&lds_v[lane4];
    float4 v1 = *(const float4*)&lds_v[256 + lane4];
    float4 v2 = *(const float4*)&lds_v[512 + lane4];
    float4 v3 = *(const float4*)&lds_v[768 + lane4];
    float4 w0 = *(const float4*)(row + lane4);
    float4 w1 = *(const float4*)(row + 256 + lane4);
    float4 w2 = *(const float4*)(row + 512 + lane4);
    float4 w3 = {0.f, 0.f, 0.f, 0.f};
    if (lane < 58) w3 = *(const float4*)(row + 768 + lane4);  // floats [768,1000)

    float s;
    s = w0.x * v0.x;        s = fmaf(w0.y, v0.y, s);
    s = fmaf(w0.z, v0.z, s); s = fmaf(w0.w, v0.w, s);
    s = fmaf(w1.x, v1.x, s); s = fmaf(w1.y, v1.y, s);
    s = fmaf(w1.z, v1.z, s); s = fmaf(w1.w, v1.w, s);
    s = fmaf(w2.x, v2.x, s); s = fmaf(w2.y, v2.y, s);
    s = fmaf(w2.z, v2.z, s); s = fmaf(w2.w, v2.w, s);
    s = fmaf(w3.x, v3.x, s); s = fmaf(w3.y, v3.y, s);
    s = fmaf(w3.z, v3.z, s); s = fmaf(w3.w, v3.w, s);
    s += __shfl_xor(s, 1);  s += __shfl_xor(s, 2);  s += __shfl_xor(s, 4);
    s += __shfl_xor(s, 8);  s += __shfl_xor(s, 16); s += __shfl_xor(s, 32);

    if (lane == 0) {
      float y = fmaxf(s + bLp[u], 0.f);
      ag_store(ws64 + ((T_STEPS + r) & 1) * EPAR + (size_t)u * 8,
               pack_entry(y, (uint32)(T_STEPS + r)));
    }
    __syncthreads();
  }

  // -------- final: WG0 computes logits + softmax --------------------------------
  if (bid == 0) {
    const uint32 sfin = (uint32)(T_STEPS + 4);
    gather4(ws64 + (sfin & 1) * EPAR, sfin, tid, lds_v, false);
    __syncthreads();

    float s = 0.f;
    if (wv < 3) {
      const float* row = Wo + (size_t)wv * HID;
      float4 v0 = *(const float4*)&lds_v[lane4];
      float4 v1 = *(const float4*)&lds_v[256 + lane4];
      float4 v2 = *(const float4*)&lds_v[512 + lane4];
      float4 v3 = *(const float4*)&lds_v[768 + lane4];
      float4 w0 = *(const float4*)(row + lane4);
      float4 w1 = *(const float4*)(row + 256 + lane4);
      float4 w2 = *(const float4*)(row + 512 + lane4);
      float4 w3 = {0.f, 0.f, 0.f, 0.f};
      if (lane < 58) w3 = *(const float4*)(row + 768 + lane4);
      s = w0.x * v0.x;        s = fmaf(w0.y, v0.y, s);
      s = fmaf(w0.z, v0.z, s); s = fmaf(w0.w, v0.w, s);
      s = fmaf(w1.x, v1.x, s); s = fmaf(w1.y, v1.y, s);
      s = fmaf(w1.z, v1.z, s); s = fmaf(w1.w, v1.w, s);
      s = fmaf(w2.x, v2.x, s); s = fmaf(w2.y, v2.y, s);
      s = fmaf(w2.z, v2.z, s); s = fmaf(w2.w, v2.w, s);
      s = fmaf(w3.x, v3.x, s); s = fmaf(w3.y, v3.y, s);
      s = fmaf(w3.z, v3.z, s); s = fmaf(w3.w, v3.w, s);
      s += __shfl_xor(s, 1);  s += __shfl_xor(s, 2);  s += __shfl_xor(s, 4);
      s += __shfl_xor(s, 8);  s += __shfl_xor(s, 16); s += __shfl_xor(s, 32);
    }
    if (wv < 3 && lane == 0) lds_log[wv] = s + bo[wv];
    __syncthreads();
    if (tid == 0) {
      float l0 = lds_log[0], l1 = lds_log[1], l2 = lds_log[2];
      float m  = fmaxf(l0, fmaxf(l1, l2));
      float e0 = __expf(l0 - m), e1 = __expf(l1 - m), e2 = __expf(l2 - m);
      float inv = 1.f / (e0 + e1 + e2);
      out[0] = e0 * inv; out[1] = e1 * inv; out[2] = e2 * inv;
    }
  }
}

extern "C" void kernel_launch(void* const* d_in, const int* in_sizes, int n_in,
                              void* d_out, int out_size, void* d_ws, size_t ws_size,
                              hipStream_t stream) {
  const float* x    = (const float*)d_in[0];
  const float* h0   = (const float*)d_in[1];
  const float* c0   = (const float*)d_in[2];
  const float* W_ih = (const float*)d_in[3];
  const float* W_hh = (const float*)d_in[4];
  const float* b_ih = (const float*)d_in[5];
  const float* b_hh = (const float*)d_in[6];
  const float* W1 = (const float*)d_in[7];
  const float* b1 = (const float*)d_in[8];
  const float* W2 = (const float*)d_in[9];
  const float* b2 = (const float*)d_in[10];
  const float* W3 = (const float*)d_in[11];
  const float* b3 = (const float*)d_in[12];
  const float* W4 = (const float*)d_in[13];
  const float* b4 = (const float*)d_in[14];
  const float* Wo = (const float*)d_in[15];
  const float* bo = (const float*)d_in[16];

  u64* ws64 = (u64*)d_ws;   // 2 parity buffers x 8192 u64 (1000 entries @ 64B stride)

  // entry buffers must start at seq=0 every launch (graph replays included)
  hipMemsetAsync(ws64, 0, 2 * EPAR * sizeof(u64), stream);

  // +16KB dynamic LDS: static ~68KB -> ~84KB total, forces 1 WG/CU (250 WGs spread)
  hipLaunchKernelGGL(lstm_mlp_kernel, dim3(NB), dim3(NTH), 16384, stream,
                     x, h0, c0, W_ih, W_hh, b_ih, b_hh,
                     W1, b1, W2, b2, W3, b3, W4, b4, Wo, bo,
                     ws64, (float*)d_out);
}